// Round 5
// baseline (299.109 us; speedup 1.0000x reference)
//
#include <hip/hip_runtime.h>

// B=2, S=2048, H=1024, NH=16, HD=64. f32 in/out; bf16 intermediates + MFMA.
// MFMA 16x16x32 bf16 layouts (m89/m91):
//   A: lane holds A[m=lane&15][k=quad*8+j]   B: B[k=quad*8+j][n=lane&15]
//   C/D: lane reg r -> row=quad*4+r, col=lane&15
typedef __bf16 bf16;
typedef __bf16 bf16x4 __attribute__((ext_vector_type(4)));
typedef __bf16 bf16x8 __attribute__((ext_vector_type(8)));
typedef float floatx4 __attribute__((ext_vector_type(4)));

#define MFMA16(a, b, c) __builtin_amdgcn_mfma_f32_16x16x32_bf16(a, b, c, 0, 0, 0)

__device__ __forceinline__ void load_lds16(const void* g, void* l) {
    // async global->LDS DMA, 16B/lane; dest = wave-uniform base + lane*16
    __builtin_amdgcn_global_load_lds(
        (const __attribute__((address_space(1))) unsigned int*)g,
        (__attribute__((address_space(3))) unsigned int*)l, 16, 0, 0);
}

__device__ __forceinline__ bf16x8 scale8(bf16x8 a, float s) {
    bf16x8 o;
    #pragma unroll
    for (int i = 0; i < 8; i++) o[i] = (bf16)((float)a[i] * s);
    return o;
}

// counted-vmcnt barrier pair (T3+T4): loads stay in flight across barriers.
#define WAITV4_BAR()  do { asm volatile("s_waitcnt vmcnt(4)" ::: "memory"); \
                           __builtin_amdgcn_s_barrier();                    \
                           __builtin_amdgcn_sched_barrier(0); } while (0)
#define WAITV0_BAR()  do { asm volatile("s_waitcnt vmcnt(0)" ::: "memory"); \
                           __builtin_amdgcn_s_barrier();                    \
                           __builtin_amdgcn_sched_barrier(0); } while (0)
#define TRAIL_BAR()   do { __builtin_amdgcn_sched_barrier(0);               \
                           asm volatile("s_waitcnt lgkmcnt(0)" ::: "memory"); \
                           __builtin_amdgcn_s_barrier(); } while (0)

// ---------------------------------------------------------------------------
// cvt: x (4096 blk), Wq/Wk/Wv/Wo (1024 blk each) f32 -> bf16
// ---------------------------------------------------------------------------
__global__ __launch_bounds__(256) void cvt_all_kernel(
    const float* __restrict__ x, const float* __restrict__ wq,
    const float* __restrict__ wk, const float* __restrict__ wv,
    const float* __restrict__ wo,
    bf16* __restrict__ xb, bf16* __restrict__ wqb, bf16* __restrict__ wkb,
    bf16* __restrict__ wvb, bf16* __restrict__ wob)
{
    int bid = blockIdx.x;
    const float* src; bf16* dst; int off;
    if (bid < 4096)      { src = x;  dst = xb;  off = bid; }
    else if (bid < 5120) { src = wq; dst = wqb; off = bid - 4096; }
    else if (bid < 6144) { src = wk; dst = wkb; off = bid - 5120; }
    else if (bid < 7168) { src = wv; dst = wvb; off = bid - 6144; }
    else                 { src = wo; dst = wob; off = bid - 7168; }
    int idx = (off * 256 + threadIdx.x) * 4;
    float4 v = *(const float4*)&src[idx];
    bf16x4 o;
    o[0] = (bf16)v.x; o[1] = (bf16)v.y; o[2] = (bf16)v.z; o[3] = (bf16)v.w;
    *(bf16x4*)&dst[idx] = o;
}

__global__ __launch_bounds__(256) void cvt_kernel(const float* __restrict__ x,
                                                  bf16* __restrict__ xb) {
    int idx = (blockIdx.x * 256 + threadIdx.x) * 4;
    float4 v = *(const float4*)&x[idx];
    bf16x4 o;
    o[0] = (bf16)v.x; o[1] = (bf16)v.y; o[2] = (bf16)v.z; o[3] = (bf16)v.w;
    *(bf16x4*)&xb[idx] = o;
}

// ===========================================================================
// FAST GEMMs V3: 2-phase BK=32 ping-pong with COUNTED vmcnt (T3+T4) + T5.
// Per step: issue prefetch(s+1) -> s_waitcnt vmcnt(4) [only current buf's
// loads] -> bare s_barrier -> ds_read + 16 MFMA (setprio 1) -> lgkmcnt(0)
// + bare s_barrier. Prefetch loads stay in flight across both barriers.
// LDS: As[2][128][32] + Bs[2][128][32] = 32KB.
// ===========================================================================

#define PREP_STAGE()                                                          \
    int u0 = w * 128 + lane;                                                  \
    int u1 = u0 + 64;                                                         \
    int r0_ = u0 >> 2, c0_ = ((u0 & 3) ^ ((r0_ >> 1) & 3)) * 8;               \
    int r1_ = u1 >> 2, c1_ = ((u1 & 3) ^ ((r1_ >> 1) & 3)) * 8;               \
    int du0 = w * 1024;                                                       \
    int du1 = du0 + 512;

#define STAGE_PF(Asrc, Bsrc, arow, brow, sbuf, kk0)                           \
    do {                                                                      \
        load_lds16(&Asrc[(size_t)((arow) + r0_) * 1024 + (kk0) + c0_],        \
                   &As[sbuf][0][0] + du0);                                    \
        load_lds16(&Asrc[(size_t)((arow) + r1_) * 1024 + (kk0) + c1_],        \
                   &As[sbuf][0][0] + du1);                                    \
        load_lds16(&Bsrc[(size_t)((brow) + r0_) * 1024 + (kk0) + c0_],        \
                   &Bs[sbuf][0][0] + du0);                                    \
        load_lds16(&Bsrc[(size_t)((brow) + r1_) * 1024 + (kk0) + c1_],        \
                   &Bs[sbuf][0][0] + du1);                                    \
    } while (0)

#define GEMM_CORE(Asrc, Bsrc, arow, brow)                                     \
    PREP_STAGE()                                                              \
    STAGE_PF(Asrc, Bsrc, arow, brow, 0, 0);                                   \
    _Pragma("unroll 2")                                                       \
    for (int s = 0; s < 32; s++) {                                            \
        int sb = s & 1;                                                       \
        if (s + 1 < 32) {                                                     \
            STAGE_PF(Asrc, Bsrc, arow, brow, sb ^ 1, (s + 1) * 32);           \
            WAITV4_BAR();                                                     \
        } else {                                                              \
            WAITV0_BAR();                                                     \
        }                                                                     \
        bf16x8 af[4], bfr[4];                                                 \
        _Pragma("unroll")                                                     \
        for (int mt = 0; mt < 4; mt++) {                                      \
            int row = wm + mt * 16 + l15;                                     \
            af[mt] = *(const bf16x8*)&As[sb][row][(quad ^ ((row >> 1) & 3)) * 8]; \
        }                                                                     \
        _Pragma("unroll")                                                     \
        for (int nt = 0; nt < 4; nt++) {                                      \
            int row = wn + nt * 16 + l15;                                     \
            bfr[nt] = *(const bf16x8*)&Bs[sb][row][(quad ^ ((row >> 1) & 3)) * 8]; \
        }                                                                     \
        __builtin_amdgcn_s_setprio(1);                                        \
        _Pragma("unroll")                                                     \
        for (int mt = 0; mt < 4; mt++)                                        \
            _Pragma("unroll")                                                 \
            for (int nt = 0; nt < 4; nt++)                                    \
                acc[mt][nt] = MFMA16(af[mt], bfr[nt], acc[mt][nt]);           \
        __builtin_amdgcn_s_setprio(0);                                        \
        TRAIL_BAR();                                                          \
    }

// ---------------------------------------------------------------------------
// QKV projection + bias + fused RoPE (q,k) + transposed V store.
// q_ws,k_ws: (B,NH,S,HD); vt_ws: (B,NH,HD,S). All-bf16 inputs.
// ---------------------------------------------------------------------------
__global__ __launch_bounds__(256) void gemm_qkv_fast(
    const bf16* __restrict__ xb,
    const bf16* __restrict__ Wq, const bf16* __restrict__ Wk,
    const bf16* __restrict__ Wv,
    const float* __restrict__ bq, const float* __restrict__ bk,
    const float* __restrict__ bv,
    bf16* __restrict__ q_ws, bf16* __restrict__ k_ws, bf16* __restrict__ vt_ws)
{
    int m0 = blockIdx.x * 128;
    int n0 = blockIdx.y * 128;
    int sec = n0 >> 10;
    int nw0 = n0 & 1023;
    const bf16* W     = (sec == 0) ? Wq : (sec == 1) ? Wk : Wv;
    const float* bias = (sec == 0) ? bq : (sec == 1) ? bk : bv;

    __shared__ bf16 As[2][128][32];
    __shared__ bf16 Bs[2][128][32];

    int tid = threadIdx.x;
    int lane = tid & 63, w = tid >> 6;
    int l15 = lane & 15, quad = lane >> 4;
    int wm = (w >> 1) * 64, wn = (w & 1) * 64;

    floatx4 acc[4][4];
    #pragma unroll
    for (int i = 0; i < 4; i++)
        #pragma unroll
        for (int j = 0; j < 4; j++) acc[i][j] = (floatx4){0.f, 0.f, 0.f, 0.f};

    GEMM_CORE(xb, W, m0, nw0)

    if (sec < 2) {
        bf16* outp = (sec == 0) ? q_ws : k_ws;
        float inv[2];
        inv[0] = __expf(-(float)l15 * (9.210340371976184f / 32.0f));
        inv[1] = __expf(-(float)(16 + l15) * (9.210340371976184f / 32.0f));
        #pragma unroll
        for (int mt = 0; mt < 4; mt++) {
            #pragma unroll
            for (int r = 0; r < 4; r++) {
                int m = m0 + wm + mt * 16 + quad * 4 + r;
                int bb = m >> 11, s = m & 2047;
                #pragma unroll
                for (int nt = 0; nt < 2; nt++) {
                    int nl1 = nw0 + wn + nt * 16 + l15;
                    int nl2 = nl1 + 32;
                    float x1 = acc[mt][nt][r] + bias[nl1];
                    float x2 = acc[mt][nt + 2][r] + bias[nl2];
                    float ang = (float)s * inv[nt];
                    float sn, cs;
                    __sincosf(ang, &sn, &cs);
                    int hh = nl1 >> 6, d = nl1 & 63;
                    size_t base = ((size_t)(bb * 16 + hh) * 2048 + s) * 64;
                    outp[base + d]      = (bf16)(x1 * cs - x2 * sn);
                    outp[base + d + 32] = (bf16)(x2 * cs + x1 * sn);
                }
            }
        }
    } else {
        #pragma unroll
        for (int mt = 0; mt < 4; mt++) {
            int mbase = m0 + wm + mt * 16 + quad * 4;
            int bb = mbase >> 11, s0 = mbase & 2047;
            #pragma unroll
            for (int nt = 0; nt < 4; nt++) {
                int nl = nw0 + wn + nt * 16 + l15;
                int hh = nl >> 6, d = nl & 63;
                bf16x4 pk;
                #pragma unroll
                for (int r = 0; r < 4; r++) pk[r] = (bf16)(acc[mt][nt][r] + bias[nl]);
                *(bf16x4*)&vt_ws[((size_t)(bb * 16 + hh) * 64 + d) * 2048 + s0] = pk;
            }
        }
    }
}

// ---------------------------------------------------------------------------
// Output projection (fast): out[m][n] = sum_k O[m][k]*Wo[n][k] + bo[n]
// ---------------------------------------------------------------------------
__global__ __launch_bounds__(256) void gemm_out_fast(
    const bf16* __restrict__ A, const bf16* __restrict__ W,
    const float* __restrict__ bias, float* __restrict__ out)
{
    int m0 = blockIdx.x * 128;
    int n0 = blockIdx.y * 128;

    __shared__ bf16 As[2][128][32];
    __shared__ bf16 Bs[2][128][32];

    int tid = threadIdx.x;
    int lane = tid & 63, w = tid >> 6;
    int l15 = lane & 15, quad = lane >> 4;
    int wm = (w >> 1) * 64, wn = (w & 1) * 64;

    floatx4 acc[4][4];
    #pragma unroll
    for (int i = 0; i < 4; i++)
        #pragma unroll
        for (int j = 0; j < 4; j++) acc[i][j] = (floatx4){0.f, 0.f, 0.f, 0.f};

    GEMM_CORE(A, W, m0, n0)

    #pragma unroll
    for (int mt = 0; mt < 4; mt++) {
        #pragma unroll
        for (int r = 0; r < 4; r++) {
            int m = m0 + wm + mt * 16 + quad * 4 + r;
            #pragma unroll
            for (int nt = 0; nt < 4; nt++) {
                int nl = n0 + wn + nt * 16 + l15;
                out[(size_t)m * 1024 + nl] = acc[mt][nt][r] + bias[nl];
            }
        }
    }
}

// ===========================================================================
// FALLBACK GEMMs (f32 W staged with in-flight cvt) — used if ws too small
// ===========================================================================
__global__ __launch_bounds__(256) void gemm_qkv_f32w(
    const bf16* __restrict__ xb,
    const float* __restrict__ Wq, const float* __restrict__ Wk,
    const float* __restrict__ Wv,
    const float* __restrict__ bq, const float* __restrict__ bk,
    const float* __restrict__ bv,
    bf16* __restrict__ q_ws, bf16* __restrict__ k_ws, bf16* __restrict__ vt_ws)
{
    int m0 = blockIdx.x * 128;
    int n0 = blockIdx.y * 128;
    int sec = n0 >> 10;
    int nw0 = n0 & 1023;
    const float* W    = (sec == 0) ? Wq : (sec == 1) ? Wk : Wv;
    const float* bias = (sec == 0) ? bq : (sec == 1) ? bk : bv;

    __shared__ bf16 As[128][72];
    __shared__ bf16 Bs[128][72];

    int tid = threadIdx.x;
    int lane = tid & 63, w = tid >> 6;
    int l15 = lane & 15, quad = lane >> 4;
    int wm = (w >> 1) * 64, wn = (w & 1) * 64;
    int sr = tid >> 1;
    int sk = (tid & 1) * 32;

    floatx4 acc[4][4];
    #pragma unroll
    for (int i = 0; i < 4; i++)
        #pragma unroll
        for (int j = 0; j < 4; j++) acc[i][j] = (floatx4){0.f, 0.f, 0.f, 0.f};

    for (int k0 = 0; k0 < 1024; k0 += 64) {
        __syncthreads();
        const bf16* ap = &xb[(size_t)(m0 + sr) * 1024 + k0 + sk];
        bf16x8 a0 = *(const bf16x8*)(ap);
        bf16x8 a1 = *(const bf16x8*)(ap + 8);
        bf16x8 a2 = *(const bf16x8*)(ap + 16);
        bf16x8 a3 = *(const bf16x8*)(ap + 24);
        const float* wp = &W[(size_t)(nw0 + sr) * 1024 + k0 + sk];
        bf16x8 bv_[4];
        #pragma unroll
        for (int c = 0; c < 4; c++) {
            float4 f0 = *(const float4*)(wp + c * 8);
            float4 f1 = *(const float4*)(wp + c * 8 + 4);
            bf16x8 t;
            t[0] = (bf16)f0.x; t[1] = (bf16)f0.y; t[2] = (bf16)f0.z; t[3] = (bf16)f0.w;
            t[4] = (bf16)f1.x; t[5] = (bf16)f1.y; t[6] = (bf16)f1.z; t[7] = (bf16)f1.w;
            bv_[c] = t;
        }
        *(bf16x8*)&As[sr][sk + 0]  = a0;
        *(bf16x8*)&As[sr][sk + 8]  = a1;
        *(bf16x8*)&As[sr][sk + 16] = a2;
        *(bf16x8*)&As[sr][sk + 24] = a3;
        #pragma unroll
        for (int c = 0; c < 4; c++) *(bf16x8*)&Bs[sr][sk + c * 8] = bv_[c];
        __syncthreads();
        #pragma unroll
        for (int kk = 0; kk < 64; kk += 32) {
            bf16x8 af[4], bfr[4];
            #pragma unroll
            for (int mt = 0; mt < 4; mt++)
                af[mt] = *(const bf16x8*)&As[wm + mt * 16 + l15][kk + quad * 8];
            #pragma unroll
            for (int nt = 0; nt < 4; nt++)
                bfr[nt] = *(const bf16x8*)&Bs[wn + nt * 16 + l15][kk + quad * 8];
            #pragma unroll
            for (int mt = 0; mt < 4; mt++)
                #pragma unroll
                for (int nt = 0; nt < 4; nt++)
                    acc[mt][nt] = MFMA16(af[mt], bfr[nt], acc[mt][nt]);
        }
    }

    if (sec < 2) {
        bf16* outp = (sec == 0) ? q_ws : k_ws;
        float inv[2];
        inv[0] = __expf(-(float)l15 * (9.210340371976184f / 32.0f));
        inv[1] = __expf(-(float)(16 + l15) * (9.210340371976184f / 32.0f));
        #pragma unroll
        for (int mt = 0; mt < 4; mt++) {
            #pragma unroll
            for (int r = 0; r < 4; r++) {
                int m = m0 + wm + mt * 16 + quad * 4 + r;
                int bb = m >> 11, s = m & 2047;
                #pragma unroll
                for (int nt = 0; nt < 2; nt++) {
                    int nl1 = nw0 + wn + nt * 16 + l15;
                    int nl2 = nl1 + 32;
                    float x1 = acc[mt][nt][r] + bias[nl1];
                    float x2 = acc[mt][nt + 2][r] + bias[nl2];
                    float ang = (float)s * inv[nt];
                    float sn, cs;
                    __sincosf(ang, &sn, &cs);
                    int hh = nl1 >> 6, d = nl1 & 63;
                    size_t base = ((size_t)(bb * 16 + hh) * 2048 + s) * 64;
                    outp[base + d]      = (bf16)(x1 * cs - x2 * sn);
                    outp[base + d + 32] = (bf16)(x2 * cs + x1 * sn);
                }
            }
        }
    } else {
        #pragma unroll
        for (int mt = 0; mt < 4; mt++) {
            int mbase = m0 + wm + mt * 16 + quad * 4;
            int bb = mbase >> 11, s0 = mbase & 2047;
            #pragma unroll
            for (int nt = 0; nt < 4; nt++) {
                int nl = nw0 + wn + nt * 16 + l15;
                int hh = nl >> 6, d = nl & 63;
                bf16x4 pk;
                #pragma unroll
                for (int r = 0; r < 4; r++) pk[r] = (bf16)(acc[mt][nt][r] + bias[nl]);
                *(bf16x4*)&vt_ws[((size_t)(bb * 16 + hh) * 64 + d) * 2048 + s0] = pk;
            }
        }
    }
}

__global__ __launch_bounds__(256) void gemm_out_f32w(
    const bf16* __restrict__ A, const float* __restrict__ W,
    const float* __restrict__ bias, float* __restrict__ out)
{
    int m0 = blockIdx.x * 128;
    int n0 = blockIdx.y * 128;

    __shared__ bf16 As[128][72];
    __shared__ bf16 Bs[128][72];

    int tid = threadIdx.x;
    int lane = tid & 63, w = tid >> 6;
    int l15 = lane & 15, quad = lane >> 4;
    int wm = (w >> 1) * 64, wn = (w & 1) * 64;
    int sr = tid >> 1;
    int sk = (tid & 1) * 32;

    floatx4 acc[4][4];
    #pragma unroll
    for (int i = 0; i < 4; i++)
        #pragma unroll
        for (int j = 0; j < 4; j++) acc[i][j] = (floatx4){0.f, 0.f, 0.f, 0.f};

    for (int k0 = 0; k0 < 1024; k0 += 64) {
        __syncthreads();
        const bf16* ap = &A[(size_t)(m0 + sr) * 1024 + k0 + sk];
        bf16x8 a0 = *(const bf16x8*)(ap);
        bf16x8 a1 = *(const bf16x8*)(ap + 8);
        bf16x8 a2 = *(const bf16x8*)(ap + 16);
        bf16x8 a3 = *(const bf16x8*)(ap + 24);
        const float* wp = &W[(size_t)(n0 + sr) * 1024 + k0 + sk];
        bf16x8 bv_[4];
        #pragma unroll
        for (int c = 0; c < 4; c++) {
            float4 f0 = *(const float4*)(wp + c * 8);
            float4 f1 = *(const float4*)(wp + c * 8 + 4);
            bf16x8 t;
            t[0] = (bf16)f0.x; t[1] = (bf16)f0.y; t[2] = (bf16)f0.z; t[3] = (bf16)f0.w;
            t[4] = (bf16)f1.x; t[5] = (bf16)f1.y; t[6] = (bf16)f1.z; t[7] = (bf16)f1.w;
            bv_[c] = t;
        }
        *(bf16x8*)&As[sr][sk + 0]  = a0;
        *(bf16x8*)&As[sr][sk + 8]  = a1;
        *(bf16x8*)&As[sr][sk + 16] = a2;
        *(bf16x8*)&As[sr][sk + 24] = a3;
        #pragma unroll
        for (int c = 0; c < 4; c++) *(bf16x8*)&Bs[sr][sk + c * 8] = bv_[c];
        __syncthreads();
        #pragma unroll
        for (int kk = 0; kk < 64; kk += 32) {
            bf16x8 af[4], bfr[4];
            #pragma unroll
            for (int mt = 0; mt < 4; mt++)
                af[mt] = *(const bf16x8*)&As[wm + mt * 16 + l15][kk + quad * 8];
            #pragma unroll
            for (int nt = 0; nt < 4; nt++)
                bfr[nt] = *(const bf16x8*)&Bs[wn + nt * 16 + l15][kk + quad * 8];
            #pragma unroll
            for (int mt = 0; mt < 4; mt++)
                #pragma unroll
                for (int nt = 0; nt < 4; nt++)
                    acc[mt][nt] = MFMA16(af[mt], bfr[nt], acc[mt][nt]);
        }
    }

    #pragma unroll
    for (int mt = 0; mt < 4; mt++) {
        #pragma unroll
        for (int r = 0; r < 4; r++) {
            int m = m0 + wm + mt * 16 + quad * 4 + r;
            #pragma unroll
            for (int nt = 0; nt < 4; nt++) {
                int nl = n0 + wn + nt * 16 + l15;
                out[(size_t)m * 1024 + nl] = acc[mt][nt][r] + bias[nl];
            }
        }
    }
}

// ---------------------------------------------------------------------------
// MFMA flash attention V5: LDS-FREE K/V (direct L2 reads), BARRIER-FREE.
// K/V are L2-resident (XCD swizzle: 4 heads/XCD = 3MB < 4MB L2; round-4
// FETCH=12.3MB proved it). Each wave reads K/V MFMA frags straight from
// global (16B/lane, full 64B-line consumption), K double-buffered in regs
// (prefetch kt+1 during QK^T of kt; static kfA/kfB naming, rule #20), V
// issued post-QK^T so softmax covers its ~200cyc L2 latency. Ps stays in
// LDS but is per-wave private -> ZERO __syncthreads; waves slip freely.
// Per-wave causal trim: nkt = (qrow+15)/64 + 1.
// LDS: Ps[8][16][72] = 18KB only.
// ---------------------------------------------------------------------------
#define ATTN_ITER(KT, KF, KN, DO_PRE)                                         \
    do {                                                                      \
        int kt0 = (KT) * 64;                                                  \
        if (DO_PRE) {                                                         \
            int kn0 = ((KT) + 1) * 64;                                        \
            _Pragma("unroll")                                                 \
            for (int kb = 0; kb < 4; kb++) {                                  \
                const bf16* kr = &kp[(size_t)(kn0 + kb * 16 + l15) * 64];     \
                KN[kb * 2]     = *(const bf16x8*)&kr[quad * 8];               \
                KN[kb * 2 + 1] = *(const bf16x8*)&kr[32 + quad * 8];          \
            }                                                                 \
        }                                                                     \
        floatx4 st[4];                                                        \
        __builtin_amdgcn_s_setprio(1);                                        \
        _Pragma("unroll")                                                     \
        for (int kb = 0; kb < 4; kb++) {                                      \
            floatx4 z = {-MFIX, -MFIX, -MFIX, -MFIX};                         \
            z = MFMA16(KF[kb * 2], qf0, z);                                   \
            z = MFMA16(KF[kb * 2 + 1], qf1, z);                               \
            st[kb] = z;                                                       \
        }                                                                     \
        __builtin_amdgcn_s_setprio(0);                                        \
        bf16x8 vf[8];                                                         \
        _Pragma("unroll")                                                     \
        for (int nt = 0; nt < 4; nt++) {                                      \
            const bf16* vr = &vp[(size_t)(nt * 16 + l15) * 2048 + kt0];       \
            vf[nt * 2]     = *(const bf16x8*)&vr[quad * 8];                   \
            vf[nt * 2 + 1] = *(const bf16x8*)&vr[32 + quad * 8];              \
        }                                                                     \
        if (kt0 + 63 > qrow) {                                                \
            int q = qrow + l15;                                               \
            _Pragma("unroll")                                                 \
            for (int kb = 0; kb < 4; kb++)                                    \
                _Pragma("unroll")                                             \
                for (int rr = 0; rr < 4; rr++) {                              \
                    int key = kt0 + kb * 16 + quad * 4 + rr;                  \
                    if (key > q) st[kb][rr] = -1e30f;                         \
                }                                                             \
        }                                                                     \
        _Pragma("unroll")                                                     \
        for (int kb = 0; kb < 4; kb++) {                                      \
            bf16x4 pk;                                                        \
            _Pragma("unroll")                                                 \
            for (int rr = 0; rr < 4; rr++) {                                  \
                float pv = exp2f(st[kb][rr]);                                 \
                l_lane += pv;                                                 \
                pk[rr] = (bf16)pv;                                            \
            }                                                                 \
            *(bf16x4*)&Ps[w][l15][kb * 16 + quad * 4] = pk;                   \
        }                                                                     \
        bf16x8 pb0 = *(const bf16x8*)&Ps[w][l15][quad * 8];                   \
        bf16x8 pb1 = *(const bf16x8*)&Ps[w][l15][32 + quad * 8];              \
        __builtin_amdgcn_s_setprio(1);                                        \
        _Pragma("unroll")                                                     \
        for (int nt = 0; nt < 4; nt++) {                                      \
            acc[nt] = MFMA16(vf[nt * 2], pb0, acc[nt]);                       \
            acc[nt] = MFMA16(vf[nt * 2 + 1], pb1, acc[nt]);                   \
        }                                                                     \
        __builtin_amdgcn_s_setprio(0);                                        \
    } while (0)

__global__ __launch_bounds__(512) void attn_kernel(
    const bf16* __restrict__ q_ws, const bf16* __restrict__ k_ws,
    const bf16* __restrict__ vt_ws, bf16* __restrict__ o_ws)
{
    __shared__ bf16 Ps[8][16][72];   // per-wave P [q][key], padded; private

    int tid = threadIdx.x;
    int w = tid >> 6, lane = tid & 63;
    int l15 = lane & 15, quad = lane >> 4;

    int bid = blockIdx.x;            // 0..511
    int g = bid & 31;                // bh; id%8==g%8 -> same XCD per bh
    int xx = bid >> 5;               // 0..15
    int qt = (xx < 8) ? xx : 23 - xx;
    if (g & 1) qt = 15 - qt;
    int bb = g >> 4, h = g & 15;
    const bf16* qp = q_ws + (size_t)g * 2048 * 64;
    const bf16* kp = k_ws + (size_t)g * 2048 * 64;
    const bf16* vp = vt_ws + (size_t)g * 64 * 2048;
    int qrow = qt * 128 + w * 16;

    const float SCL = 0.125f * 1.4426950408889634f;   // (1/sqrt(HD))*log2(e)
    const float MFIX = 20.0f;        // fixed exp2-domain shift (folded in C-init)

    // Q B-frags resident, pre-scaled
    bf16x8 qf0 = scale8(*(const bf16x8*)&qp[(size_t)(qrow + l15) * 64 + quad * 8], SCL);
    bf16x8 qf1 = scale8(*(const bf16x8*)&qp[(size_t)(qrow + l15) * 64 + 32 + quad * 8], SCL);

    float l_lane = 0.f;
    floatx4 acc[4];
    #pragma unroll
    for (int nt = 0; nt < 4; nt++) acc[nt] = (floatx4){0.f, 0.f, 0.f, 0.f};

    int nkt = ((qrow + 15) >> 6) + 1;   // per-wave causal trim (1..32)

    // preload K(0) into kfA
    bf16x8 kfA[8], kfB[8];
    #pragma unroll
    for (int kb = 0; kb < 4; kb++) {
        const bf16* kr = &kp[(size_t)(kb * 16 + l15) * 64];
        kfA[kb * 2]     = *(const bf16x8*)&kr[quad * 8];
        kfA[kb * 2 + 1] = *(const bf16x8*)&kr[32 + quad * 8];
    }

    int kt = 0;
    for (; kt + 1 < nkt; kt += 2) {
        ATTN_ITER(kt, kfA, kfB, true);
        ATTN_ITER(kt + 1, kfB, kfA, (kt + 2 < nkt));
    }
    if (kt < nkt) ATTN_ITER(kt, kfA, kfB, false);

    // single cross-lane reduce: sum l over the 4 quads (same query l15)
    l_lane += __shfl_xor(l_lane, 16, 64);
    l_lane += __shfl_xor(l_lane, 32, 64);
    float inv = 1.f / l_lane;
    int s = qrow + l15;
    #pragma unroll
    for (int nt = 0; nt < 4; nt++) {
        bf16x4 pk;
        #pragma unroll
        for (int rr = 0; rr < 4; rr++) pk[rr] = (bf16)(acc[nt][rr] * inv);
        *(bf16x4*)&o_ws[((size_t)(bb * 2048 + s)) * 1024 + h * 64 + nt * 16 + quad * 4] = pk;
    }
}

// ---------------------------------------------------------------------------
extern "C" void kernel_launch(void* const* d_in, const int* in_sizes, int n_in,
                              void* d_out, int out_size, void* d_ws, size_t ws_size,
                              hipStream_t stream) {
    const float* x  = (const float*)d_in[0];
    const float* Wq = (const float*)d_in[1];
    const float* bq = (const float*)d_in[2];
    const float* Wk = (const float*)d_in[3];
    const float* bk = (const float*)d_in[4];
    const float* Wv = (const float*)d_in[5];
    const float* bv = (const float*)d_in[6];
    const float* Wo = (const float*)d_in[7];
    const float* bo = (const float*)d_in[8];
    float* out = (float*)d_out;

    const size_t NELEM = (size_t)2 * 2048 * 1024;   // 4,194,304
    const size_t WELEM = (size_t)1024 * 1024;
    bf16* xb    = (bf16*)d_ws;          // 8MB; reused as o_ws after qkv
    bf16* q_ws  = xb + NELEM;
    bf16* k_ws  = q_ws + NELEM;
    bf16* vt_ws = k_ws + NELEM;         // (B,NH,HD,S)
    bf16* o_ws  = xb;
    bf16* wqb   = vt_ws + NELEM;        // +2MB each
    bf16* wkb   = wqb + WELEM;
    bf16* wvb   = wkb + WELEM;
    bf16* wob   = wvb + WELEM;          // ends at 40MB

    bool fast = ws_size >= (size_t)40 * 1024 * 1024;   // constant across calls

    if (fast) {
        cvt_all_kernel<<<8192, 256, 0, stream>>>(x, Wq, Wk, Wv, Wo,
                                                 xb, wqb, wkb, wvb, wob);
        gemm_qkv_fast<<<dim3(32, 24), 256, 0, stream>>>(
            xb, wqb, wkb, wvb, bq, bk, bv, q_ws, k_ws, vt_ws);
        attn_kernel<<<512, 512, 0, stream>>>(q_ws, k_ws, vt_ws, o_ws);
        gemm_out_fast<<<dim3(32, 8), 256, 0, stream>>>(o_ws, wob, bo, out);
    } else {
        cvt_kernel<<<4096, 256, 0, stream>>>(x, xb);
        gemm_qkv_f32w<<<dim3(32, 24), 256, 0, stream>>>(
            xb, Wq, Wk, Wv, bq, bk, bv, q_ws, k_ws, vt_ws);
        attn_kernel<<<512, 512, 0, stream>>>(q_ws, k_ws, vt_ws, o_ws);
        gemm_out_f32w<<<dim3(32, 8), 256, 0, stream>>>(o_ws, Wo, bo, out);
    }
}

// Round 6
// 197.907 us; speedup vs baseline: 1.5114x; 1.5114x over previous
//
#include <hip/hip_runtime.h>

// B=2, S=2048, H=1024, NH=16, HD=64. f32 in/out; bf16 intermediates + MFMA.
// MFMA 16x16x32 bf16 layouts (m89/m91):
//   A: lane holds A[m=lane&15][k=quad*8+j]   B: B[k=quad*8+j][n=lane&15]
//   C/D: lane reg r -> row=quad*4+r, col=lane&15
typedef __bf16 bf16;
typedef __bf16 bf16x4 __attribute__((ext_vector_type(4)));
typedef __bf16 bf16x8 __attribute__((ext_vector_type(8)));
typedef float floatx4 __attribute__((ext_vector_type(4)));

#define MFMA16(a, b, c) __builtin_amdgcn_mfma_f32_16x16x32_bf16(a, b, c, 0, 0, 0)

__device__ __forceinline__ void load_lds16(const void* g, void* l) {
    // async global->LDS DMA, 16B/lane; dest = wave-uniform base + lane*16
    __builtin_amdgcn_global_load_lds(
        (const __attribute__((address_space(1))) unsigned int*)g,
        (__attribute__((address_space(3))) unsigned int*)l, 16, 0, 0);
}

__device__ __forceinline__ bf16x8 scale8(bf16x8 a, float s) {
    bf16x8 o;
    #pragma unroll
    for (int i = 0; i < 8; i++) o[i] = (bf16)((float)a[i] * s);
    return o;
}

// counted-vmcnt barrier pair (T3+T4): loads stay in flight across barriers.
#define WAITV4_BAR()  do { asm volatile("s_waitcnt vmcnt(4)" ::: "memory"); \
                           __builtin_amdgcn_s_barrier();                    \
                           __builtin_amdgcn_sched_barrier(0); } while (0)
#define WAITV2_BAR()  do { asm volatile("s_waitcnt vmcnt(2)" ::: "memory"); \
                           __builtin_amdgcn_s_barrier();                    \
                           __builtin_amdgcn_sched_barrier(0); } while (0)
#define WAITV0_BAR()  do { asm volatile("s_waitcnt vmcnt(0)" ::: "memory"); \
                           __builtin_amdgcn_s_barrier();                    \
                           __builtin_amdgcn_sched_barrier(0); } while (0)
#define TRAIL_BAR()   do { __builtin_amdgcn_sched_barrier(0);               \
                           asm volatile("s_waitcnt lgkmcnt(0)" ::: "memory"); \
                           __builtin_amdgcn_s_barrier(); } while (0)

// ---------------------------------------------------------------------------
// cvt: x (4096 blk), Wq/Wk/Wv/Wo (1024 blk each) f32 -> bf16
// ---------------------------------------------------------------------------
__global__ __launch_bounds__(256) void cvt_all_kernel(
    const float* __restrict__ x, const float* __restrict__ wq,
    const float* __restrict__ wk, const float* __restrict__ wv,
    const float* __restrict__ wo,
    bf16* __restrict__ xb, bf16* __restrict__ wqb, bf16* __restrict__ wkb,
    bf16* __restrict__ wvb, bf16* __restrict__ wob)
{
    int bid = blockIdx.x;
    const float* src; bf16* dst; int off;
    if (bid < 4096)      { src = x;  dst = xb;  off = bid; }
    else if (bid < 5120) { src = wq; dst = wqb; off = bid - 4096; }
    else if (bid < 6144) { src = wk; dst = wkb; off = bid - 5120; }
    else if (bid < 7168) { src = wv; dst = wvb; off = bid - 6144; }
    else                 { src = wo; dst = wob; off = bid - 7168; }
    int idx = (off * 256 + threadIdx.x) * 4;
    float4 v = *(const float4*)&src[idx];
    bf16x4 o;
    o[0] = (bf16)v.x; o[1] = (bf16)v.y; o[2] = (bf16)v.z; o[3] = (bf16)v.w;
    *(bf16x4*)&dst[idx] = o;
}

__global__ __launch_bounds__(256) void cvt_kernel(const float* __restrict__ x,
                                                  bf16* __restrict__ xb) {
    int idx = (blockIdx.x * 256 + threadIdx.x) * 4;
    float4 v = *(const float4*)&x[idx];
    bf16x4 o;
    o[0] = (bf16)v.x; o[1] = (bf16)v.y; o[2] = (bf16)v.z; o[3] = (bf16)v.w;
    *(bf16x4*)&xb[idx] = o;
}

// ===========================================================================
// FAST GEMMs V3: 2-phase BK=32 ping-pong with COUNTED vmcnt (T3+T4) + T5.
// (unchanged from round 4 — verified fast)
// ===========================================================================

#define PREP_STAGE()                                                          \
    int u0 = w * 128 + lane;                                                  \
    int u1 = u0 + 64;                                                         \
    int r0_ = u0 >> 2, c0_ = ((u0 & 3) ^ ((r0_ >> 1) & 3)) * 8;               \
    int r1_ = u1 >> 2, c1_ = ((u1 & 3) ^ ((r1_ >> 1) & 3)) * 8;               \
    int du0 = w * 1024;                                                       \
    int du1 = du0 + 512;

#define STAGE_PF(Asrc, Bsrc, arow, brow, sbuf, kk0)                           \
    do {                                                                      \
        load_lds16(&Asrc[(size_t)((arow) + r0_) * 1024 + (kk0) + c0_],        \
                   &As[sbuf][0][0] + du0);                                    \
        load_lds16(&Asrc[(size_t)((arow) + r1_) * 1024 + (kk0) + c1_],        \
                   &As[sbuf][0][0] + du1);                                    \
        load_lds16(&Bsrc[(size_t)((brow) + r0_) * 1024 + (kk0) + c0_],        \
                   &Bs[sbuf][0][0] + du0);                                    \
        load_lds16(&Bsrc[(size_t)((brow) + r1_) * 1024 + (kk0) + c1_],        \
                   &Bs[sbuf][0][0] + du1);                                    \
    } while (0)

#define GEMM_CORE(Asrc, Bsrc, arow, brow)                                     \
    PREP_STAGE()                                                              \
    STAGE_PF(Asrc, Bsrc, arow, brow, 0, 0);                                   \
    _Pragma("unroll 2")                                                       \
    for (int s = 0; s < 32; s++) {                                            \
        int sb = s & 1;                                                       \
        if (s + 1 < 32) {                                                     \
            STAGE_PF(Asrc, Bsrc, arow, brow, sb ^ 1, (s + 1) * 32);           \
            WAITV4_BAR();                                                     \
        } else {                                                              \
            WAITV0_BAR();                                                     \
        }                                                                     \
        bf16x8 af[4], bfr[4];                                                 \
        _Pragma("unroll")                                                     \
        for (int mt = 0; mt < 4; mt++) {                                      \
            int row = wm + mt * 16 + l15;                                     \
            af[mt] = *(const bf16x8*)&As[sb][row][(quad ^ ((row >> 1) & 3)) * 8]; \
        }                                                                     \
        _Pragma("unroll")                                                     \
        for (int nt = 0; nt < 4; nt++) {                                      \
            int row = wn + nt * 16 + l15;                                     \
            bfr[nt] = *(const bf16x8*)&Bs[sb][row][(quad ^ ((row >> 1) & 3)) * 8]; \
        }                                                                     \
        __builtin_amdgcn_s_setprio(1);                                        \
        _Pragma("unroll")                                                     \
        for (int mt = 0; mt < 4; mt++)                                        \
            _Pragma("unroll")                                                 \
            for (int nt = 0; nt < 4; nt++)                                    \
                acc[mt][nt] = MFMA16(af[mt], bfr[nt], acc[mt][nt]);           \
        __builtin_amdgcn_s_setprio(0);                                        \
        TRAIL_BAR();                                                          \
    }

// ---------------------------------------------------------------------------
// QKV projection + bias + fused RoPE (q,k) + transposed V store.
// q_ws,k_ws: (B,NH,S,HD); vt_ws: (B,NH,HD,S). All-bf16 inputs.
// ---------------------------------------------------------------------------
__global__ __launch_bounds__(256) void gemm_qkv_fast(
    const bf16* __restrict__ xb,
    const bf16* __restrict__ Wq, const bf16* __restrict__ Wk,
    const bf16* __restrict__ Wv,
    const float* __restrict__ bq, const float* __restrict__ bk,
    const float* __restrict__ bv,
    bf16* __restrict__ q_ws, bf16* __restrict__ k_ws, bf16* __restrict__ vt_ws)
{
    int m0 = blockIdx.x * 128;
    int n0 = blockIdx.y * 128;
    int sec = n0 >> 10;
    int nw0 = n0 & 1023;
    const bf16* W     = (sec == 0) ? Wq : (sec == 1) ? Wk : Wv;
    const float* bias = (sec == 0) ? bq : (sec == 1) ? bk : bv;

    __shared__ bf16 As[2][128][32];
    __shared__ bf16 Bs[2][128][32];

    int tid = threadIdx.x;
    int lane = tid & 63, w = tid >> 6;
    int l15 = lane & 15, quad = lane >> 4;
    int wm = (w >> 1) * 64, wn = (w & 1) * 64;

    floatx4 acc[4][4];
    #pragma unroll
    for (int i = 0; i < 4; i++)
        #pragma unroll
        for (int j = 0; j < 4; j++) acc[i][j] = (floatx4){0.f, 0.f, 0.f, 0.f};

    GEMM_CORE(xb, W, m0, nw0)

    if (sec < 2) {
        bf16* outp = (sec == 0) ? q_ws : k_ws;
        float inv[2];
        inv[0] = __expf(-(float)l15 * (9.210340371976184f / 32.0f));
        inv[1] = __expf(-(float)(16 + l15) * (9.210340371976184f / 32.0f));
        #pragma unroll
        for (int mt = 0; mt < 4; mt++) {
            #pragma unroll
            for (int r = 0; r < 4; r++) {
                int m = m0 + wm + mt * 16 + quad * 4 + r;
                int bb = m >> 11, s = m & 2047;
                #pragma unroll
                for (int nt = 0; nt < 2; nt++) {
                    int nl1 = nw0 + wn + nt * 16 + l15;
                    int nl2 = nl1 + 32;
                    float x1 = acc[mt][nt][r] + bias[nl1];
                    float x2 = acc[mt][nt + 2][r] + bias[nl2];
                    float ang = (float)s * inv[nt];
                    float sn, cs;
                    __sincosf(ang, &sn, &cs);
                    int hh = nl1 >> 6, d = nl1 & 63;
                    size_t base = ((size_t)(bb * 16 + hh) * 2048 + s) * 64;
                    outp[base + d]      = (bf16)(x1 * cs - x2 * sn);
                    outp[base + d + 32] = (bf16)(x2 * cs + x1 * sn);
                }
            }
        }
    } else {
        #pragma unroll
        for (int mt = 0; mt < 4; mt++) {
            int mbase = m0 + wm + mt * 16 + quad * 4;
            int bb = mbase >> 11, s0 = mbase & 2047;
            #pragma unroll
            for (int nt = 0; nt < 4; nt++) {
                int nl = nw0 + wn + nt * 16 + l15;
                int hh = nl >> 6, d = nl & 63;
                bf16x4 pk;
                #pragma unroll
                for (int r = 0; r < 4; r++) pk[r] = (bf16)(acc[mt][nt][r] + bias[nl]);
                *(bf16x4*)&vt_ws[((size_t)(bb * 16 + hh) * 64 + d) * 2048 + s0] = pk;
            }
        }
    }
}

// ---------------------------------------------------------------------------
// Output projection (fast): out[m][n] = sum_k O[m][k]*Wo[n][k] + bo[n]
// ---------------------------------------------------------------------------
__global__ __launch_bounds__(256) void gemm_out_fast(
    const bf16* __restrict__ A, const bf16* __restrict__ W,
    const float* __restrict__ bias, float* __restrict__ out)
{
    int m0 = blockIdx.x * 128;
    int n0 = blockIdx.y * 128;

    __shared__ bf16 As[2][128][32];
    __shared__ bf16 Bs[2][128][32];

    int tid = threadIdx.x;
    int lane = tid & 63, w = tid >> 6;
    int l15 = lane & 15, quad = lane >> 4;
    int wm = (w >> 1) * 64, wn = (w & 1) * 64;

    floatx4 acc[4][4];
    #pragma unroll
    for (int i = 0; i < 4; i++)
        #pragma unroll
        for (int j = 0; j < 4; j++) acc[i][j] = (floatx4){0.f, 0.f, 0.f, 0.f};

    GEMM_CORE(A, W, m0, n0)

    #pragma unroll
    for (int mt = 0; mt < 4; mt++) {
        #pragma unroll
        for (int r = 0; r < 4; r++) {
            int m = m0 + wm + mt * 16 + quad * 4 + r;
            #pragma unroll
            for (int nt = 0; nt < 4; nt++) {
                int nl = n0 + wn + nt * 16 + l15;
                out[(size_t)m * 1024 + nl] = acc[mt][nt][r] + bias[nl];
            }
        }
    }
}

// ===========================================================================
// FALLBACK GEMMs (f32 W staged with in-flight cvt) — used if ws too small
// ===========================================================================
__global__ __launch_bounds__(256) void gemm_qkv_f32w(
    const bf16* __restrict__ xb,
    const float* __restrict__ Wq, const float* __restrict__ Wk,
    const float* __restrict__ Wv,
    const float* __restrict__ bq, const float* __restrict__ bk,
    const float* __restrict__ bv,
    bf16* __restrict__ q_ws, bf16* __restrict__ k_ws, bf16* __restrict__ vt_ws)
{
    int m0 = blockIdx.x * 128;
    int n0 = blockIdx.y * 128;
    int sec = n0 >> 10;
    int nw0 = n0 & 1023;
    const float* W    = (sec == 0) ? Wq : (sec == 1) ? Wk : Wv;
    const float* bias = (sec == 0) ? bq : (sec == 1) ? bk : bv;

    __shared__ bf16 As[128][72];
    __shared__ bf16 Bs[128][72];

    int tid = threadIdx.x;
    int lane = tid & 63, w = tid >> 6;
    int l15 = lane & 15, quad = lane >> 4;
    int wm = (w >> 1) * 64, wn = (w & 1) * 64;
    int sr = tid >> 1;
    int sk = (tid & 1) * 32;

    floatx4 acc[4][4];
    #pragma unroll
    for (int i = 0; i < 4; i++)
        #pragma unroll
        for (int j = 0; j < 4; j++) acc[i][j] = (floatx4){0.f, 0.f, 0.f, 0.f};

    for (int k0 = 0; k0 < 1024; k0 += 64) {
        __syncthreads();
        const bf16* ap = &xb[(size_t)(m0 + sr) * 1024 + k0 + sk];
        bf16x8 a0 = *(const bf16x8*)(ap);
        bf16x8 a1 = *(const bf16x8*)(ap + 8);
        bf16x8 a2 = *(const bf16x8*)(ap + 16);
        bf16x8 a3 = *(const bf16x8*)(ap + 24);
        const float* wp = &W[(size_t)(nw0 + sr) * 1024 + k0 + sk];
        bf16x8 bv_[4];
        #pragma unroll
        for (int c = 0; c < 4; c++) {
            float4 f0 = *(const float4*)(wp + c * 8);
            float4 f1 = *(const float4*)(wp + c * 8 + 4);
            bf16x8 t;
            t[0] = (bf16)f0.x; t[1] = (bf16)f0.y; t[2] = (bf16)f0.z; t[3] = (bf16)f0.w;
            t[4] = (bf16)f1.x; t[5] = (bf16)f1.y; t[6] = (bf16)f1.z; t[7] = (bf16)f1.w;
            bv_[c] = t;
        }
        *(bf16x8*)&As[sr][sk + 0]  = a0;
        *(bf16x8*)&As[sr][sk + 8]  = a1;
        *(bf16x8*)&As[sr][sk + 16] = a2;
        *(bf16x8*)&As[sr][sk + 24] = a3;
        #pragma unroll
        for (int c = 0; c < 4; c++) *(bf16x8*)&Bs[sr][sk + c * 8] = bv_[c];
        __syncthreads();
        #pragma unroll
        for (int kk = 0; kk < 64; kk += 32) {
            bf16x8 af[4], bfr[4];
            #pragma unroll
            for (int mt = 0; mt < 4; mt++)
                af[mt] = *(const bf16x8*)&As[wm + mt * 16 + l15][kk + quad * 8];
            #pragma unroll
            for (int nt = 0; nt < 4; nt++)
                bfr[nt] = *(const bf16x8*)&Bs[wn + nt * 16 + l15][kk + quad * 8];
            #pragma unroll
            for (int mt = 0; mt < 4; mt++)
                #pragma unroll
                for (int nt = 0; nt < 4; nt++)
                    acc[mt][nt] = MFMA16(af[mt], bfr[nt], acc[mt][nt]);
        }
    }

    if (sec < 2) {
        bf16* outp = (sec == 0) ? q_ws : k_ws;
        float inv[2];
        inv[0] = __expf(-(float)l15 * (9.210340371976184f / 32.0f));
        inv[1] = __expf(-(float)(16 + l15) * (9.210340371976184f / 32.0f));
        #pragma unroll
        for (int mt = 0; mt < 4; mt++) {
            #pragma unroll
            for (int r = 0; r < 4; r++) {
                int m = m0 + wm + mt * 16 + quad * 4 + r;
                int bb = m >> 11, s = m & 2047;
                #pragma unroll
                for (int nt = 0; nt < 2; nt++) {
                    int nl1 = nw0 + wn + nt * 16 + l15;
                    int nl2 = nl1 + 32;
                    float x1 = acc[mt][nt][r] + bias[nl1];
                    float x2 = acc[mt][nt + 2][r] + bias[nl2];
                    float ang = (float)s * inv[nt];
                    float sn, cs;
                    __sincosf(ang, &sn, &cs);
                    int hh = nl1 >> 6, d = nl1 & 63;
                    size_t base = ((size_t)(bb * 16 + hh) * 2048 + s) * 64;
                    outp[base + d]      = (bf16)(x1 * cs - x2 * sn);
                    outp[base + d + 32] = (bf16)(x2 * cs + x1 * sn);
                }
            }
        }
    } else {
        #pragma unroll
        for (int mt = 0; mt < 4; mt++) {
            int mbase = m0 + wm + mt * 16 + quad * 4;
            int bb = mbase >> 11, s0 = mbase & 2047;
            #pragma unroll
            for (int nt = 0; nt < 4; nt++) {
                int nl = nw0 + wn + nt * 16 + l15;
                int hh = nl >> 6, d = nl & 63;
                bf16x4 pk;
                #pragma unroll
                for (int r = 0; r < 4; r++) pk[r] = (bf16)(acc[mt][nt][r] + bias[nl]);
                *(bf16x4*)&vt_ws[((size_t)(bb * 16 + hh) * 64 + d) * 2048 + s0] = pk;
            }
        }
    }
}

__global__ __launch_bounds__(256) void gemm_out_f32w(
    const bf16* __restrict__ A, const float* __restrict__ W,
    const float* __restrict__ bias, float* __restrict__ out)
{
    int m0 = blockIdx.x * 128;
    int n0 = blockIdx.y * 128;

    __shared__ bf16 As[128][72];
    __shared__ bf16 Bs[128][72];

    int tid = threadIdx.x;
    int lane = tid & 63, w = tid >> 6;
    int l15 = lane & 15, quad = lane >> 4;
    int wm = (w >> 1) * 64, wn = (w & 1) * 64;
    int sr = tid >> 1;
    int sk = (tid & 1) * 32;

    floatx4 acc[4][4];
    #pragma unroll
    for (int i = 0; i < 4; i++)
        #pragma unroll
        for (int j = 0; j < 4; j++) acc[i][j] = (floatx4){0.f, 0.f, 0.f, 0.f};

    for (int k0 = 0; k0 < 1024; k0 += 64) {
        __syncthreads();
        const bf16* ap = &A[(size_t)(m0 + sr) * 1024 + k0 + sk];
        bf16x8 a0 = *(const bf16x8*)(ap);
        bf16x8 a1 = *(const bf16x8*)(ap + 8);
        bf16x8 a2 = *(const bf16x8*)(ap + 16);
        bf16x8 a3 = *(const bf16x8*)(ap + 24);
        const float* wp = &W[(size_t)(n0 + sr) * 1024 + k0 + sk];
        bf16x8 bv_[4];
        #pragma unroll
        for (int c = 0; c < 4; c++) {
            float4 f0 = *(const float4*)(wp + c * 8);
            float4 f1 = *(const float4*)(wp + c * 8 + 4);
            bf16x8 t;
            t[0] = (bf16)f0.x; t[1] = (bf16)f0.y; t[2] = (bf16)f0.z; t[3] = (bf16)f0.w;
            t[4] = (bf16)f1.x; t[5] = (bf16)f1.y; t[6] = (bf16)f1.z; t[7] = (bf16)f1.w;
            bv_[c] = t;
        }
        *(bf16x8*)&As[sr][sk + 0]  = a0;
        *(bf16x8*)&As[sr][sk + 8]  = a1;
        *(bf16x8*)&As[sr][sk + 16] = a2;
        *(bf16x8*)&As[sr][sk + 24] = a3;
        #pragma unroll
        for (int c = 0; c < 4; c++) *(bf16x8*)&Bs[sr][sk + c * 8] = bv_[c];
        __syncthreads();
        #pragma unroll
        for (int kk = 0; kk < 64; kk += 32) {
            bf16x8 af[4], bfr[4];
            #pragma unroll
            for (int mt = 0; mt < 4; mt++)
                af[mt] = *(const bf16x8*)&As[wm + mt * 16 + l15][kk + quad * 8];
            #pragma unroll
            for (int nt = 0; nt < 4; nt++)
                bfr[nt] = *(const bf16x8*)&Bs[wn + nt * 16 + l15][kk + quad * 8];
            #pragma unroll
            for (int mt = 0; mt < 4; mt++)
                #pragma unroll
                for (int nt = 0; nt < 4; nt++)
                    acc[mt][nt] = MFMA16(af[mt], bfr[nt], acc[mt][nt]);
        }
    }

    #pragma unroll
    for (int mt = 0; mt < 4; mt++) {
        #pragma unroll
        for (int r = 0; r < 4; r++) {
            int m = m0 + wm + mt * 16 + quad * 4 + r;
            #pragma unroll
            for (int nt = 0; nt < 4; nt++) {
                int nl = n0 + wn + nt * 16 + l15;
                out[(size_t)m * 1024 + nl] = acc[mt][nt][r] + bias[nl];
            }
        }
    }
}

// ---------------------------------------------------------------------------
// MFMA flash attention V6: V4 structure + 2-WAY KEY-SPLIT per tile.
// Waves (wq,wk): wq in 0..3 owns 32 queries, wk in 0..1 owns a 32-key half.
// Each wave reads HALF of K and V per tile (4+4 b128 vs 8+8) -> LDS-pipe
// pressure (the modeled bottleneck of V4) drops ~36%. Fixed-max softmax is
// linear, so key-halves combine once at the end: O=(accA+accB)/(lA+lB) via a
// 32KB scratch overlaid on the freed K/V LDS + one __syncthreads.
// Staging schedule (counted-vmcnt ping-pong), XCD swizzle, makespan pairing,
// exp2/MFMA counts: unchanged from V4.
// LDS: Ks[2]+Vt[2] 32KB + Ps 18KB + Lx 0.5KB = 50.5KB -> 2 blocks/CU.
// ---------------------------------------------------------------------------
__global__ __launch_bounds__(512, 4) void attn_kernel(
    const bf16* __restrict__ q_ws, const bf16* __restrict__ k_ws,
    const bf16* __restrict__ vt_ws, bf16* __restrict__ o_ws)
{
    __shared__ __align__(16) char smem[32768];           // Ks/Vt; epilogue scratch
    bf16 (*Ks)[64][64] = (bf16(*)[64][64])smem;          // [2][64][64]
    bf16 (*Vt)[64][64] = (bf16(*)[64][64])(smem + 16384);
    __shared__ bf16 Ps[4][32][72];                       // per-wq P [q][key]
    __shared__ float Lx[4][2][16];                       // wk=1 partial l

    int tid = threadIdx.x;
    int w = tid >> 6, lane = tid & 63;
    int l15 = lane & 15, quad = lane >> 4;
    int wq = w & 3, wk = w >> 2;

    int bid = blockIdx.x;            // 0..511
    int g = bid & 31;                // bh; id%8==g%8 -> same XCD per bh
    int xx = bid >> 5;               // 0..15
    int qt = (xx < 8) ? xx : 23 - xx;
    if (g & 1) qt = 15 - qt;
    int bb = g >> 4, h = g & 15;
    const bf16* qp = q_ws + (size_t)g * 2048 * 64;
    const bf16* kp = k_ws + (size_t)g * 2048 * 64;
    const bf16* vp = vt_ws + (size_t)g * 64 * 2048;
    int qbase = qt * 128 + wq * 32;  // wave's 32 queries: qbase + qs*16 + l15

    // staging map: wave w stages segment w (8 rows) of K and of V (as V4).
    int r = w * 8 + (lane >> 3);
    int c = (lane & 7) ^ (r & 7);
    int od = w * 512;                // bf16 offset of wave's segment

    const float SCL = 0.125f * 1.4426950408889634f;   // (1/sqrt(HD))*log2(e)
    const float MFIX = 20.0f;        // fixed exp2-domain shift (folded in C-init)

    // Q B-frags for 2 query sub-blocks, pre-scaled
    bf16x8 qf[2][2];
    #pragma unroll
    for (int qs = 0; qs < 2; qs++) {
        const bf16* qr = &qp[(size_t)(qbase + qs * 16 + l15) * 64];
        qf[qs][0] = scale8(*(const bf16x8*)&qr[quad * 8], SCL);
        qf[qs][1] = scale8(*(const bf16x8*)&qr[32 + quad * 8], SCL);
    }

    float l_lane[2] = {0.f, 0.f};
    floatx4 acc[4][2];
    #pragma unroll
    for (int db = 0; db < 4; db++)
        #pragma unroll
        for (int qs = 0; qs < 2; qs++) acc[db][qs] = (floatx4){0.f, 0.f, 0.f, 0.f};

    int nkt = 2 * qt + 2;            // key tiles 0..2qt+1 cover q-tile qt

    // prologue: stage kt=0 into buf 0
    load_lds16(&kp[(size_t)r * 64 + c * 8], &Ks[0][0][0] + od);
    load_lds16(&vp[(size_t)r * 2048 + c * 8], &Vt[0][0][0] + od);

    for (int kt = 0; kt < nkt; kt++) {
        int buf = kt & 1;
        if (kt + 1 < nkt) {
            int kn0 = (kt + 1) * 64;
            load_lds16(&kp[(size_t)(kn0 + r) * 64 + c * 8], &Ks[buf ^ 1][0][0] + od);
            load_lds16(&vp[(size_t)r * 2048 + kn0 + c * 8], &Vt[buf ^ 1][0][0] + od);
            WAITV2_BAR();
        } else {
            WAITV0_BAR();
        }

        int kt0 = kt * 64;

        // QK^T on own key half: 2 kb x 2 qs, K-dim 64 via 2 MFMA
        floatx4 st[2][2];
        #pragma unroll
        for (int kb = 0; kb < 2; kb++) {
            int row = wk * 32 + kb * 16 + l15;
            int rx = row & 7;
            bf16x8 a0 = *(const bf16x8*)&Ks[buf][row][(quad ^ rx) * 8];
            bf16x8 a1 = *(const bf16x8*)&Ks[buf][row][((quad + 4) ^ rx) * 8];
            __builtin_amdgcn_s_setprio(1);
            #pragma unroll
            for (int qs = 0; qs < 2; qs++) {
                floatx4 z = {-MFIX, -MFIX, -MFIX, -MFIX};
                z = MFMA16(a0, qf[qs][0], z);
                z = MFMA16(a1, qf[qs][1], z);
                st[kb][qs] = z;
            }
            __builtin_amdgcn_s_setprio(0);
        }

        // causal mask (exact, per element) when this wave's key half can
        // exceed its smallest query
        if (kt0 + wk * 32 + 31 > qbase) {
            #pragma unroll
            for (int kb = 0; kb < 2; kb++)
                #pragma unroll
                for (int qs = 0; qs < 2; qs++) {
                    int q = qbase + qs * 16 + l15;
                    #pragma unroll
                    for (int rr = 0; rr < 4; rr++) {
                        int key = kt0 + wk * 32 + kb * 16 + quad * 4 + rr;
                        if (key > q) st[kb][qs][rr] = -1e30f;
                    }
                }
        }

        // fixed-max softmax: no reductions, no rescale in the loop
        #pragma unroll
        for (int kb = 0; kb < 2; kb++)
            #pragma unroll
            for (int qs = 0; qs < 2; qs++) {
                bf16x4 pk;
                #pragma unroll
                for (int rr = 0; rr < 4; rr++) {
                    float pv = exp2f(st[kb][qs][rr]);
                    l_lane[qs] += pv;
                    pk[rr] = (bf16)pv;
                }
                *(bf16x4*)&Ps[wq][qs * 16 + l15][wk * 32 + kb * 16 + quad * 4] = pk;
            }

        // PV on own key half: B-operand from OWN wave's Ps writes only
        bf16x8 pb0 = *(const bf16x8*)&Ps[wq][l15][wk * 32 + quad * 8];
        bf16x8 pb1 = *(const bf16x8*)&Ps[wq][16 + l15][wk * 32 + quad * 8];
        __builtin_amdgcn_s_setprio(1);
        #pragma unroll
        for (int db = 0; db < 4; db++) {
            int row = db * 16 + l15;
            int rx = row & 7;
            int ch = (wk * 4 + quad) ^ rx;
            bf16x8 v = *(const bf16x8*)&Vt[buf][row][ch * 8];
            acc[db][0] = MFMA16(v, pb0, acc[db][0]);
            acc[db][1] = MFMA16(v, pb1, acc[db][1]);
        }
        __builtin_amdgcn_s_setprio(0);

        TRAIL_BAR();
    }

    // quad-reduce l (all quads end with the per-query sum)
    #pragma unroll
    for (int qs = 0; qs < 2; qs++) {
        l_lane[qs] += __shfl_xor(l_lane[qs], 16, 64);
        l_lane[qs] += __shfl_xor(l_lane[qs], 32, 64);
    }

    // cross-half combine: wk=1 publishes acc+l; wk=0 sums, normalizes, stores.
    float* scr = (float*)smem;       // K/V LDS is dead past the last TRAIL_BAR
    if (wk == 1) {
        #pragma unroll
        for (int db = 0; db < 4; db++)
            #pragma unroll
            for (int qs = 0; qs < 2; qs++)
                *(floatx4*)&scr[((wq * 8 + db * 2 + qs) * 64 + lane) * 4] = acc[db][qs];
        Lx[wq][0][l15] = l_lane[0];
        Lx[wq][1][l15] = l_lane[1];
    }
    __syncthreads();
    if (wk == 0) {
        float inv[2];
        #pragma unroll
        for (int qs = 0; qs < 2; qs++)
            inv[qs] = 1.f / (l_lane[qs] + Lx[wq][qs][l15]);
        #pragma unroll
        for (int db = 0; db < 4; db++)
            #pragma unroll
            for (int qs = 0; qs < 2; qs++) {
                floatx4 o = *(const floatx4*)&scr[((wq * 8 + db * 2 + qs) * 64 + lane) * 4];
                bf16x4 pk;
                #pragma unroll
                for (int rr = 0; rr < 4; rr++)
                    pk[rr] = (bf16)((acc[db][qs][rr] + o[rr]) * inv[qs]);
                int s = qbase + qs * 16 + l15;
                *(bf16x4*)&o_ws[((size_t)(bb * 2048 + s)) * 1024 + h * 64 + db * 16 + quad * 4] = pk;
            }
    }
}

// ---------------------------------------------------------------------------
extern "C" void kernel_launch(void* const* d_in, const int* in_sizes, int n_in,
                              void* d_out, int out_size, void* d_ws, size_t ws_size,
                              hipStream_t stream) {
    const float* x  = (const float*)d_in[0];
    const float* Wq = (const float*)d_in[1];
    const float* bq = (const float*)d_in[2];
    const float* Wk = (const float*)d_in[3];
    const float* bk = (const float*)d_in[4];
    const float* Wv = (const float*)d_in[5];
    const float* bv = (const float*)d_in[6];
    const float* Wo = (const float*)d_in[7];
    const float* bo = (const float*)d_in[8];
    float* out = (float*)d_out;

    const size_t NELEM = (size_t)2 * 2048 * 1024;   // 4,194,304
    const size_t WELEM = (size_t)1024 * 1024;
    bf16* xb    = (bf16*)d_ws;          // 8MB; reused as o_ws after qkv
    bf16* q_ws  = xb + NELEM;
    bf16* k_ws  = q_ws + NELEM;
    bf16* vt_ws = k_ws + NELEM;         // (B,NH,HD,S)
    bf16* o_ws  = xb;
    bf16* wqb   = vt_ws + NELEM;        // +2MB each
    bf16* wkb   = wqb + WELEM;
    bf16* wvb   = wkb + WELEM;
    bf16* wob   = wvb + WELEM;          // ends at 40MB

    bool fast = ws_size >= (size_t)40 * 1024 * 1024;   // constant across calls

    if (fast) {
        cvt_all_kernel<<<8192, 256, 0, stream>>>(x, Wq, Wk, Wv, Wo,
                                                 xb, wqb, wkb, wvb, wob);
        gemm_qkv_fast<<<dim3(32, 24), 256, 0, stream>>>(
            xb, wqb, wkb, wvb, bq, bk, bv, q_ws, k_ws, vt_ws);
        attn_kernel<<<512, 512, 0, stream>>>(q_ws, k_ws, vt_ws, o_ws);
        gemm_out_fast<<<dim3(32, 8), 256, 0, stream>>>(o_ws, wob, bo, out);
    } else {
        cvt_kernel<<<4096, 256, 0, stream>>>(x, xb);
        gemm_qkv_f32w<<<dim3(32, 24), 256, 0, stream>>>(
            xb, Wq, Wk, Wv, bq, bk, bv, q_ws, k_ws, vt_ws);
        attn_kernel<<<512, 512, 0, stream>>>(q_ws, k_ws, vt_ws, o_ws);
        gemm_out_f32w<<<dim3(32, 8), 256, 0, stream>>>(o_ws, Wo, bo, out);
    }
}

// Round 7
// 194.470 us; speedup vs baseline: 1.5381x; 1.0177x over previous
//
#include <hip/hip_runtime.h>

// B=2, S=2048, H=1024, NH=16, HD=64. f32 in/out; bf16 intermediates + MFMA.
// MFMA 16x16x32 bf16 layouts (m89/m91):
//   A: lane holds A[m=lane&15][k=quad*8+j]   B: B[k=quad*8+j][n=lane&15]
//   C/D: lane reg r -> row=quad*4+r, col=lane&15
typedef __bf16 bf16;
typedef __bf16 bf16x4 __attribute__((ext_vector_type(4)));
typedef __bf16 bf16x8 __attribute__((ext_vector_type(8)));
typedef float floatx4 __attribute__((ext_vector_type(4)));

#define MFMA16(a, b, c) __builtin_amdgcn_mfma_f32_16x16x32_bf16(a, b, c, 0, 0, 0)

__device__ __forceinline__ void load_lds16(const void* g, void* l) {
    // async global->LDS DMA, 16B/lane; dest = wave-uniform base + lane*16
    __builtin_amdgcn_global_load_lds(
        (const __attribute__((address_space(1))) unsigned int*)g,
        (__attribute__((address_space(3))) unsigned int*)l, 16, 0, 0);
}

__device__ __forceinline__ bf16x8 scale8(bf16x8 a, float s) {
    bf16x8 o;
    #pragma unroll
    for (int i = 0; i < 8; i++) o[i] = (bf16)((float)a[i] * s);
    return o;
}

// counted-vmcnt barrier pair (T3+T4): loads stay in flight across barriers.
#define WAITV4_BAR()  do { asm volatile("s_waitcnt vmcnt(4)" ::: "memory"); \
                           __builtin_amdgcn_s_barrier();                    \
                           __builtin_amdgcn_sched_barrier(0); } while (0)
#define WAITV0_BAR()  do { asm volatile("s_waitcnt vmcnt(0)" ::: "memory"); \
                           __builtin_amdgcn_s_barrier();                    \
                           __builtin_amdgcn_sched_barrier(0); } while (0)
#define TRAIL_BAR()   do { __builtin_amdgcn_sched_barrier(0);               \
                           asm volatile("s_waitcnt lgkmcnt(0)" ::: "memory"); \
                           __builtin_amdgcn_s_barrier(); } while (0)

// ---------------------------------------------------------------------------
// cvt: x (4096 blk), Wq/Wk/Wv/Wo (1024 blk each) f32 -> bf16
// ---------------------------------------------------------------------------
__global__ __launch_bounds__(256) void cvt_all_kernel(
    const float* __restrict__ x, const float* __restrict__ wq,
    const float* __restrict__ wk, const float* __restrict__ wv,
    const float* __restrict__ wo,
    bf16* __restrict__ xb, bf16* __restrict__ wqb, bf16* __restrict__ wkb,
    bf16* __restrict__ wvb, bf16* __restrict__ wob)
{
    int bid = blockIdx.x;
    const float* src; bf16* dst; int off;
    if (bid < 4096)      { src = x;  dst = xb;  off = bid; }
    else if (bid < 5120) { src = wq; dst = wqb; off = bid - 4096; }
    else if (bid < 6144) { src = wk; dst = wkb; off = bid - 5120; }
    else if (bid < 7168) { src = wv; dst = wvb; off = bid - 6144; }
    else                 { src = wo; dst = wob; off = bid - 7168; }
    int idx = (off * 256 + threadIdx.x) * 4;
    float4 v = *(const float4*)&src[idx];
    bf16x4 o;
    o[0] = (bf16)v.x; o[1] = (bf16)v.y; o[2] = (bf16)v.z; o[3] = (bf16)v.w;
    *(bf16x4*)&dst[idx] = o;
}

__global__ __launch_bounds__(256) void cvt_kernel(const float* __restrict__ x,
                                                  bf16* __restrict__ xb) {
    int idx = (blockIdx.x * 256 + threadIdx.x) * 4;
    float4 v = *(const float4*)&x[idx];
    bf16x4 o;
    o[0] = (bf16)v.x; o[1] = (bf16)v.y; o[2] = (bf16)v.z; o[3] = (bf16)v.w;
    *(bf16x4*)&xb[idx] = o;
}

// ===========================================================================
// FAST GEMMs V3: 2-phase BK=32 ping-pong with COUNTED vmcnt (T3+T4) + T5.
// (unchanged from round 4 — verified fast)
// ===========================================================================

#define PREP_STAGE()                                                          \
    int u0 = w * 128 + lane;                                                  \
    int u1 = u0 + 64;                                                         \
    int r0_ = u0 >> 2, c0_ = ((u0 & 3) ^ ((r0_ >> 1) & 3)) * 8;               \
    int r1_ = u1 >> 2, c1_ = ((u1 & 3) ^ ((r1_ >> 1) & 3)) * 8;               \
    int du0 = w * 1024;                                                       \
    int du1 = du0 + 512;

#define STAGE_PF(Asrc, Bsrc, arow, brow, sbuf, kk0)                           \
    do {                                                                      \
        load_lds16(&Asrc[(size_t)((arow) + r0_) * 1024 + (kk0) + c0_],        \
                   &As[sbuf][0][0] + du0);                                    \
        load_lds16(&Asrc[(size_t)((arow) + r1_) * 1024 + (kk0) + c1_],        \
                   &As[sbuf][0][0] + du1);                                    \
        load_lds16(&Bsrc[(size_t)((brow) + r0_) * 1024 + (kk0) + c0_],        \
                   &Bs[sbuf][0][0] + du0);                                    \
        load_lds16(&Bsrc[(size_t)((brow) + r1_) * 1024 + (kk0) + c1_],        \
                   &Bs[sbuf][0][0] + du1);                                    \
    } while (0)

#define GEMM_CORE(Asrc, Bsrc, arow, brow)                                     \
    PREP_STAGE()                                                              \
    STAGE_PF(Asrc, Bsrc, arow, brow, 0, 0);                                   \
    _Pragma("unroll 2")                                                       \
    for (int s = 0; s < 32; s++) {                                            \
        int sb = s & 1;                                                       \
        if (s + 1 < 32) {                                                     \
            STAGE_PF(Asrc, Bsrc, arow, brow, sb ^ 1, (s + 1) * 32);           \
            WAITV4_BAR();                                                     \
        } else {                                                              \
            WAITV0_BAR();                                                     \
        }                                                                     \
        bf16x8 af[4], bfr[4];                                                 \
        _Pragma("unroll")                                                     \
        for (int mt = 0; mt < 4; mt++) {                                      \
            int row = wm + mt * 16 + l15;                                     \
            af[mt] = *(const bf16x8*)&As[sb][row][(quad ^ ((row >> 1) & 3)) * 8]; \
        }                                                                     \
        _Pragma("unroll")                                                     \
        for (int nt = 0; nt < 4; nt++) {                                      \
            int row = wn + nt * 16 + l15;                                     \
            bfr[nt] = *(const bf16x8*)&Bs[sb][row][(quad ^ ((row >> 1) & 3)) * 8]; \
        }                                                                     \
        __builtin_amdgcn_s_setprio(1);                                        \
        _Pragma("unroll")                                                     \
        for (int mt = 0; mt < 4; mt++)                                        \
            _Pragma("unroll")                                                 \
            for (int nt = 0; nt < 4; nt++)                                    \
                acc[mt][nt] = MFMA16(af[mt], bfr[nt], acc[mt][nt]);           \
        __builtin_amdgcn_s_setprio(0);                                        \
        TRAIL_BAR();                                                          \
    }

// ---------------------------------------------------------------------------
// QKV projection + bias + fused RoPE (q,k) + transposed V store.
// q_ws,k_ws: (B,NH,S,HD); vt_ws: (B,NH,HD,S). All-bf16 inputs.
// ---------------------------------------------------------------------------
__global__ __launch_bounds__(256) void gemm_qkv_fast(
    const bf16* __restrict__ xb,
    const bf16* __restrict__ Wq, const bf16* __restrict__ Wk,
    const bf16* __restrict__ Wv,
    const float* __restrict__ bq, const float* __restrict__ bk,
    const float* __restrict__ bv,
    bf16* __restrict__ q_ws, bf16* __restrict__ k_ws, bf16* __restrict__ vt_ws)
{
    int m0 = blockIdx.x * 128;
    int n0 = blockIdx.y * 128;
    int sec = n0 >> 10;
    int nw0 = n0 & 1023;
    const bf16* W     = (sec == 0) ? Wq : (sec == 1) ? Wk : Wv;
    const float* bias = (sec == 0) ? bq : (sec == 1) ? bk : bv;

    __shared__ bf16 As[2][128][32];
    __shared__ bf16 Bs[2][128][32];

    int tid = threadIdx.x;
    int lane = tid & 63, w = tid >> 6;
    int l15 = lane & 15, quad = lane >> 4;
    int wm = (w >> 1) * 64, wn = (w & 1) * 64;

    floatx4 acc[4][4];
    #pragma unroll
    for (int i = 0; i < 4; i++)
        #pragma unroll
        for (int j = 0; j < 4; j++) acc[i][j] = (floatx4){0.f, 0.f, 0.f, 0.f};

    GEMM_CORE(xb, W, m0, nw0)

    if (sec < 2) {
        bf16* outp = (sec == 0) ? q_ws : k_ws;
        float inv[2];
        inv[0] = __expf(-(float)l15 * (9.210340371976184f / 32.0f));
        inv[1] = __expf(-(float)(16 + l15) * (9.210340371976184f / 32.0f));
        #pragma unroll
        for (int mt = 0; mt < 4; mt++) {
            #pragma unroll
            for (int r = 0; r < 4; r++) {
                int m = m0 + wm + mt * 16 + quad * 4 + r;
                int bb = m >> 11, s = m & 2047;
                #pragma unroll
                for (int nt = 0; nt < 2; nt++) {
                    int nl1 = nw0 + wn + nt * 16 + l15;
                    int nl2 = nl1 + 32;
                    float x1 = acc[mt][nt][r] + bias[nl1];
                    float x2 = acc[mt][nt + 2][r] + bias[nl2];
                    float ang = (float)s * inv[nt];
                    float sn, cs;
                    __sincosf(ang, &sn, &cs);
                    int hh = nl1 >> 6, d = nl1 & 63;
                    size_t base = ((size_t)(bb * 16 + hh) * 2048 + s) * 64;
                    outp[base + d]      = (bf16)(x1 * cs - x2 * sn);
                    outp[base + d + 32] = (bf16)(x2 * cs + x1 * sn);
                }
            }
        }
    } else {
        #pragma unroll
        for (int mt = 0; mt < 4; mt++) {
            int mbase = m0 + wm + mt * 16 + quad * 4;
            int bb = mbase >> 11, s0 = mbase & 2047;
            #pragma unroll
            for (int nt = 0; nt < 4; nt++) {
                int nl = nw0 + wn + nt * 16 + l15;
                int hh = nl >> 6, d = nl & 63;
                bf16x4 pk;
                #pragma unroll
                for (int r = 0; r < 4; r++) pk[r] = (bf16)(acc[mt][nt][r] + bias[nl]);
                *(bf16x4*)&vt_ws[((size_t)(bb * 16 + hh) * 64 + d) * 2048 + s0] = pk;
            }
        }
    }
}

// ---------------------------------------------------------------------------
// Output projection (fast): out[m][n] = sum_k O[m][k]*Wo[n][k] + bo[n]
// ---------------------------------------------------------------------------
__global__ __launch_bounds__(256) void gemm_out_fast(
    const bf16* __restrict__ A, const bf16* __restrict__ W,
    const float* __restrict__ bias, float* __restrict__ out)
{
    int m0 = blockIdx.x * 128;
    int n0 = blockIdx.y * 128;

    __shared__ bf16 As[2][128][32];
    __shared__ bf16 Bs[2][128][32];

    int tid = threadIdx.x;
    int lane = tid & 63, w = tid >> 6;
    int l15 = lane & 15, quad = lane >> 4;
    int wm = (w >> 1) * 64, wn = (w & 1) * 64;

    floatx4 acc[4][4];
    #pragma unroll
    for (int i = 0; i < 4; i++)
        #pragma unroll
        for (int j = 0; j < 4; j++) acc[i][j] = (floatx4){0.f, 0.f, 0.f, 0.f};

    GEMM_CORE(A, W, m0, n0)

    #pragma unroll
    for (int mt = 0; mt < 4; mt++) {
        #pragma unroll
        for (int r = 0; r < 4; r++) {
            int m = m0 + wm + mt * 16 + quad * 4 + r;
            #pragma unroll
            for (int nt = 0; nt < 4; nt++) {
                int nl = n0 + wn + nt * 16 + l15;
                out[(size_t)m * 1024 + nl] = acc[mt][nt][r] + bias[nl];
            }
        }
    }
}

// ===========================================================================
// FALLBACK GEMMs (f32 W staged with in-flight cvt) — used if ws too small
// ===========================================================================
__global__ __launch_bounds__(256) void gemm_qkv_f32w(
    const bf16* __restrict__ xb,
    const float* __restrict__ Wq, const float* __restrict__ Wk,
    const float* __restrict__ Wv,
    const float* __restrict__ bq, const float* __restrict__ bk,
    const float* __restrict__ bv,
    bf16* __restrict__ q_ws, bf16* __restrict__ k_ws, bf16* __restrict__ vt_ws)
{
    int m0 = blockIdx.x * 128;
    int n0 = blockIdx.y * 128;
    int sec = n0 >> 10;
    int nw0 = n0 & 1023;
    const float* W    = (sec == 0) ? Wq : (sec == 1) ? Wk : Wv;
    const float* bias = (sec == 0) ? bq : (sec == 1) ? bk : bv;

    __shared__ bf16 As[128][72];
    __shared__ bf16 Bs[128][72];

    int tid = threadIdx.x;
    int lane = tid & 63, w = tid >> 6;
    int l15 = lane & 15, quad = lane >> 4;
    int wm = (w >> 1) * 64, wn = (w & 1) * 64;
    int sr = tid >> 1;
    int sk = (tid & 1) * 32;

    floatx4 acc[4][4];
    #pragma unroll
    for (int i = 0; i < 4; i++)
        #pragma unroll
        for (int j = 0; j < 4; j++) acc[i][j] = (floatx4){0.f, 0.f, 0.f, 0.f};

    for (int k0 = 0; k0 < 1024; k0 += 64) {
        __syncthreads();
        const bf16* ap = &xb[(size_t)(m0 + sr) * 1024 + k0 + sk];
        bf16x8 a0 = *(const bf16x8*)(ap);
        bf16x8 a1 = *(const bf16x8*)(ap + 8);
        bf16x8 a2 = *(const bf16x8*)(ap + 16);
        bf16x8 a3 = *(const bf16x8*)(ap + 24);
        const float* wp = &W[(size_t)(nw0 + sr) * 1024 + k0 + sk];
        bf16x8 bv_[4];
        #pragma unroll
        for (int c = 0; c < 4; c++) {
            float4 f0 = *(const float4*)(wp + c * 8);
            float4 f1 = *(const float4*)(wp + c * 8 + 4);
            bf16x8 t;
            t[0] = (bf16)f0.x; t[1] = (bf16)f0.y; t[2] = (bf16)f0.z; t[3] = (bf16)f0.w;
            t[4] = (bf16)f1.x; t[5] = (bf16)f1.y; t[6] = (bf16)f1.z; t[7] = (bf16)f1.w;
            bv_[c] = t;
        }
        *(bf16x8*)&As[sr][sk + 0]  = a0;
        *(bf16x8*)&As[sr][sk + 8]  = a1;
        *(bf16x8*)&As[sr][sk + 16] = a2;
        *(bf16x8*)&As[sr][sk + 24] = a3;
        #pragma unroll
        for (int c = 0; c < 4; c++) *(bf16x8*)&Bs[sr][sk + c * 8] = bv_[c];
        __syncthreads();
        #pragma unroll
        for (int kk = 0; kk < 64; kk += 32) {
            bf16x8 af[4], bfr[4];
            #pragma unroll
            for (int mt = 0; mt < 4; mt++)
                af[mt] = *(const bf16x8*)&As[wm + mt * 16 + l15][kk + quad * 8];
            #pragma unroll
            for (int nt = 0; nt < 4; nt++)
                bfr[nt] = *(const bf16x8*)&Bs[wn + nt * 16 + l15][kk + quad * 8];
            #pragma unroll
            for (int mt = 0; mt < 4; mt++)
                #pragma unroll
                for (int nt = 0; nt < 4; nt++)
                    acc[mt][nt] = MFMA16(af[mt], bfr[nt], acc[mt][nt]);
        }
    }

    if (sec < 2) {
        bf16* outp = (sec == 0) ? q_ws : k_ws;
        float inv[2];
        inv[0] = __expf(-(float)l15 * (9.210340371976184f / 32.0f));
        inv[1] = __expf(-(float)(16 + l15) * (9.210340371976184f / 32.0f));
        #pragma unroll
        for (int mt = 0; mt < 4; mt++) {
            #pragma unroll
            for (int r = 0; r < 4; r++) {
                int m = m0 + wm + mt * 16 + quad * 4 + r;
                int bb = m >> 11, s = m & 2047;
                #pragma unroll
                for (int nt = 0; nt < 2; nt++) {
                    int nl1 = nw0 + wn + nt * 16 + l15;
                    int nl2 = nl1 + 32;
                    float x1 = acc[mt][nt][r] + bias[nl1];
                    float x2 = acc[mt][nt + 2][r] + bias[nl2];
                    float ang = (float)s * inv[nt];
                    float sn, cs;
                    __sincosf(ang, &sn, &cs);
                    int hh = nl1 >> 6, d = nl1 & 63;
                    size_t base = ((size_t)(bb * 16 + hh) * 2048 + s) * 64;
                    outp[base + d]      = (bf16)(x1 * cs - x2 * sn);
                    outp[base + d + 32] = (bf16)(x2 * cs + x1 * sn);
                }
            }
        }
    } else {
        #pragma unroll
        for (int mt = 0; mt < 4; mt++) {
            int mbase = m0 + wm + mt * 16 + quad * 4;
            int bb = mbase >> 11, s0 = mbase & 2047;
            #pragma unroll
            for (int nt = 0; nt < 4; nt++) {
                int nl = nw0 + wn + nt * 16 + l15;
                int hh = nl >> 6, d = nl & 63;
                bf16x4 pk;
                #pragma unroll
                for (int r = 0; r < 4; r++) pk[r] = (bf16)(acc[mt][nt][r] + bias[nl]);
                *(bf16x4*)&vt_ws[((size_t)(bb * 16 + hh) * 64 + d) * 2048 + s0] = pk;
            }
        }
    }
}

__global__ __launch_bounds__(256) void gemm_out_f32w(
    const bf16* __restrict__ A, const float* __restrict__ W,
    const float* __restrict__ bias, float* __restrict__ out)
{
    int m0 = blockIdx.x * 128;
    int n0 = blockIdx.y * 128;

    __shared__ bf16 As[128][72];
    __shared__ bf16 Bs[128][72];

    int tid = threadIdx.x;
    int lane = tid & 63, w = tid >> 6;
    int l15 = lane & 15, quad = lane >> 4;
    int wm = (w >> 1) * 64, wn = (w & 1) * 64;
    int sr = tid >> 1;
    int sk = (tid & 1) * 32;

    floatx4 acc[4][4];
    #pragma unroll
    for (int i = 0; i < 4; i++)
        #pragma unroll
        for (int j = 0; j < 4; j++) acc[i][j] = (floatx4){0.f, 0.f, 0.f, 0.f};

    for (int k0 = 0; k0 < 1024; k0 += 64) {
        __syncthreads();
        const bf16* ap = &A[(size_t)(m0 + sr) * 1024 + k0 + sk];
        bf16x8 a0 = *(const bf16x8*)(ap);
        bf16x8 a1 = *(const bf16x8*)(ap + 8);
        bf16x8 a2 = *(const bf16x8*)(ap + 16);
        bf16x8 a3 = *(const bf16x8*)(ap + 24);
        const float* wp = &W[(size_t)(n0 + sr) * 1024 + k0 + sk];
        bf16x8 bv_[4];
        #pragma unroll
        for (int c = 0; c < 4; c++) {
            float4 f0 = *(const float4*)(wp + c * 8);
            float4 f1 = *(const float4*)(wp + c * 8 + 4);
            bf16x8 t;
            t[0] = (bf16)f0.x; t[1] = (bf16)f0.y; t[2] = (bf16)f0.z; t[3] = (bf16)f0.w;
            t[4] = (bf16)f1.x; t[5] = (bf16)f1.y; t[6] = (bf16)f1.z; t[7] = (bf16)f1.w;
            bv_[c] = t;
        }
        *(bf16x8*)&As[sr][sk + 0]  = a0;
        *(bf16x8*)&As[sr][sk + 8]  = a1;
        *(bf16x8*)&As[sr][sk + 16] = a2;
        *(bf16x8*)&As[sr][sk + 24] = a3;
        #pragma unroll
        for (int c = 0; c < 4; c++) *(bf16x8*)&Bs[sr][sk + c * 8] = bv_[c];
        __syncthreads();
        #pragma unroll
        for (int kk = 0; kk < 64; kk += 32) {
            bf16x8 af[4], bfr[4];
            #pragma unroll
            for (int mt = 0; mt < 4; mt++)
                af[mt] = *(const bf16x8*)&As[wm + mt * 16 + l15][kk + quad * 8];
            #pragma unroll
            for (int nt = 0; nt < 4; nt++)
                bfr[nt] = *(const bf16x8*)&Bs[wn + nt * 16 + l15][kk + quad * 8];
            #pragma unroll
            for (int mt = 0; mt < 4; mt++)
                #pragma unroll
                for (int nt = 0; nt < 4; nt++)
                    acc[mt][nt] = MFMA16(af[mt], bfr[nt], acc[mt][nt]);
        }
    }

    #pragma unroll
    for (int mt = 0; mt < 4; mt++) {
        #pragma unroll
        for (int r = 0; r < 4; r++) {
            int m = m0 + wm + mt * 16 + quad * 4 + r;
            #pragma unroll
            for (int nt = 0; nt < 4; nt++) {
                int nl = n0 + wn + nt * 16 + l15;
                out[(size_t)m * 1024 + nl] = acc[mt][nt][r] + bias[nl];
            }
        }
    }
}

// ---------------------------------------------------------------------------
// MFMA flash attention V7: QBLK=64, 4 waves, BACKFILL GRID.
// Round-6 lesson: 512 blocks = exactly 2/CU, no backfill -> straggler CUs run
// a lone 8-wave block for up to 30 iters (occupancy 24%). V7: 1024 blocks
// (32 qtiles x 32 bh), 41KB LDS -> 3 resident/CU + queue; qt = 31-x so the
// longest blocks (32 iters) dispatch FIRST and short blocks fill the tail.
// Kept from V4/V6: XCD swizzle (g=bid&31 -> bid%8=g%8, 4 heads/XCD in L2),
// counted-vmcnt double-buffer ping-pong (4 loads/wave -> vmcnt(4)),
// fixed-max softmax with MFIX in C-init, setprio around MFMA.
// LDS: Ks[2]+Vt[2] 32KB + Ps[4] 9KB = 41KB.
// ---------------------------------------------------------------------------
__global__ __launch_bounds__(256) void attn_kernel(
    const bf16* __restrict__ q_ws, const bf16* __restrict__ k_ws,
    const bf16* __restrict__ vt_ws, bf16* __restrict__ o_ws)
{
    __shared__ bf16 Ks[2][64][64];   // [buf][key][d], chunk-swizzled
    __shared__ bf16 Vt[2][64][64];   // [buf][d][key], chunk-swizzled
    __shared__ bf16 Ps[4][16][72];   // per-wave P [q][key], padded

    int tid = threadIdx.x;
    int w = tid >> 6, lane = tid & 63;
    int l15 = lane & 15, quad = lane >> 4;

    int bid = blockIdx.x;            // 0..1023
    int g = bid & 31;                // bh; bid%8==g%8 -> same XCD per bh
    int x = bid >> 5;                // 0..31
    int qt = 31 - x;                 // longest-first dispatch order
    int bb = g >> 4, h = g & 15;
    const bf16* qp = q_ws + (size_t)g * 2048 * 64;
    const bf16* kp = k_ws + (size_t)g * 2048 * 64;
    const bf16* vp = vt_ws + (size_t)g * 64 * 2048;
    int qrow = qt * 64 + w * 16;

    // staging map: wave w stages segments {2w,2w+1} (16 rows) of K and V.
    // 16B units: gidx = seg*64+lane; row = gidx>>3; pchunk = gidx&7;
    // source chunk c = pchunk ^ (row&7) pre-swizzled; LDS dest linear.
    int g0 = (w * 2) * 64 + lane;
    int g1 = g0 + 64;
    int r0 = g0 >> 3, c0 = (g0 & 7) ^ (r0 & 7);
    int r1 = g1 >> 3, c1 = (g1 & 7) ^ (r1 & 7);
    int o0 = (w * 2) * 512;          // bf16 offset of wave's segment 0
    int o1 = o0 + 512;

    const float SCL = 0.125f * 1.4426950408889634f;   // (1/sqrt(HD))*log2(e)
    const float MFIX = 20.0f;        // fixed exp2-domain shift (folded in C-init)

    // Q B-frags resident, pre-scaled
    bf16x8 qf0 = scale8(*(const bf16x8*)&qp[(size_t)(qrow + l15) * 64 + quad * 8], SCL);
    bf16x8 qf1 = scale8(*(const bf16x8*)&qp[(size_t)(qrow + l15) * 64 + 32 + quad * 8], SCL);

    float l_lane = 0.f;
    floatx4 acc[4];
    #pragma unroll
    for (int nt = 0; nt < 4; nt++) acc[nt] = (floatx4){0.f, 0.f, 0.f, 0.f};

    int nkt = qt + 1;                // key tiles 0..qt cover q-tile qt

    // prologue: stage kt=0 into buf 0
    load_lds16(&kp[(size_t)r0 * 64 + c0 * 8], &Ks[0][0][0] + o0);
    load_lds16(&kp[(size_t)r1 * 64 + c1 * 8], &Ks[0][0][0] + o1);
    load_lds16(&vp[(size_t)r0 * 2048 + c0 * 8], &Vt[0][0][0] + o0);
    load_lds16(&vp[(size_t)r1 * 2048 + c1 * 8], &Vt[0][0][0] + o1);

    for (int kt = 0; kt < nkt; kt++) {
        int buf = kt & 1;
        // issue prefetch kt+1 into buf^1, then counted publish of buf
        if (kt + 1 < nkt) {
            int kn0 = (kt + 1) * 64;
            load_lds16(&kp[(size_t)(kn0 + r0) * 64 + c0 * 8], &Ks[buf ^ 1][0][0] + o0);
            load_lds16(&kp[(size_t)(kn0 + r1) * 64 + c1 * 8], &Ks[buf ^ 1][0][0] + o1);
            load_lds16(&vp[(size_t)r0 * 2048 + kn0 + c0 * 8], &Vt[buf ^ 1][0][0] + o0);
            load_lds16(&vp[(size_t)r1 * 2048 + kn0 + c1 * 8], &Vt[buf ^ 1][0][0] + o1);
            WAITV4_BAR();
        } else {
            WAITV0_BAR();
        }

        int kt0 = kt * 64;

        // S^T = K * Q^T : per lane 4 keys (quad*4+r) x 1 query (l15).
        floatx4 st[4];
        #pragma unroll
        for (int kb = 0; kb < 4; kb++) {
            int row = kb * 16 + l15;
            int rx = row & 7;
            bf16x8 a0 = *(const bf16x8*)&Ks[buf][row][(quad ^ rx) * 8];
            bf16x8 a1 = *(const bf16x8*)&Ks[buf][row][((quad + 4) ^ rx) * 8];
            floatx4 z = {-MFIX, -MFIX, -MFIX, -MFIX};
            __builtin_amdgcn_s_setprio(1);
            z = MFMA16(a0, qf0, z);
            z = MFMA16(a1, qf1, z);
            __builtin_amdgcn_s_setprio(0);
            st[kb] = z;
        }
        if (kt0 + 63 > qrow) {   // diagonal/above tile for this wave: causal mask
            int q = qrow + l15;
            #pragma unroll
            for (int kb = 0; kb < 4; kb++)
                #pragma unroll
                for (int rr = 0; rr < 4; rr++) {
                    int key = kt0 + kb * 16 + quad * 4 + rr;
                    if (key > q) st[kb][rr] = -1e30f;
                }
        }

        // fixed-max softmax: no reductions, no rescale in the loop
        #pragma unroll
        for (int kb = 0; kb < 4; kb++) {
            bf16x4 pk;
            #pragma unroll
            for (int rr = 0; rr < 4; rr++) {
                float pv = exp2f(st[kb][rr]);
                l_lane += pv;
                pk[rr] = (bf16)pv;
            }
            *(bf16x4*)&Ps[w][l15][kb * 16 + quad * 4] = pk;
        }

        // O^T += V^T * P^T  (A = V^T rows d, B = P^T cols q)
        bf16x8 pb0 = *(const bf16x8*)&Ps[w][l15][quad * 8];
        bf16x8 pb1 = *(const bf16x8*)&Ps[w][l15][32 + quad * 8];
        __builtin_amdgcn_s_setprio(1);
        #pragma unroll
        for (int nt = 0; nt < 4; nt++) {
            int row = nt * 16 + l15;
            int rx = row & 7;
            bf16x8 v0 = *(const bf16x8*)&Vt[buf][row][(quad ^ rx) * 8];
            bf16x8 v1 = *(const bf16x8*)&Vt[buf][row][((quad + 4) ^ rx) * 8];
            acc[nt] = MFMA16(v0, pb0, acc[nt]);
            acc[nt] = MFMA16(v1, pb1, acc[nt]);
        }
        __builtin_amdgcn_s_setprio(0);

        TRAIL_BAR();
    }

    // single cross-lane reduce: sum l over the 4 quads (same query l15)
    l_lane += __shfl_xor(l_lane, 16, 64);
    l_lane += __shfl_xor(l_lane, 32, 64);
    float inv = 1.f / l_lane;
    int s = qrow + l15;
    #pragma unroll
    for (int nt = 0; nt < 4; nt++) {
        bf16x4 pk;
        #pragma unroll
        for (int rr = 0; rr < 4; rr++) pk[rr] = (bf16)(acc[nt][rr] * inv);
        *(bf16x4*)&o_ws[((size_t)(bb * 2048 + s)) * 1024 + h * 64 + nt * 16 + quad * 4] = pk;
    }
}

// ---------------------------------------------------------------------------
extern "C" void kernel_launch(void* const* d_in, const int* in_sizes, int n_in,
                              void* d_out, int out_size, void* d_ws, size_t ws_size,
                              hipStream_t stream) {
    const float* x  = (const float*)d_in[0];
    const float* Wq = (const float*)d_in[1];
    const float* bq = (const float*)d_in[2];
    const float* Wk = (const float*)d_in[3];
    const float* bk = (const float*)d_in[4];
    const float* Wv = (const float*)d_in[5];
    const float* bv = (const float*)d_in[6];
    const float* Wo = (const float*)d_in[7];
    const float* bo = (const float*)d_in[8];
    float* out = (float*)d_out;

    const size_t NELEM = (size_t)2 * 2048 * 1024;   // 4,194,304
    const size_t WELEM = (size_t)1024 * 1024;
    bf16* xb    = (bf16*)d_ws;          // 8MB; reused as o_ws after qkv
    bf16* q_ws  = xb + NELEM;
    bf16* k_ws  = q_ws + NELEM;
    bf16* vt_ws = k_ws + NELEM;         // (B,NH,HD,S)
    bf16* o_ws  = xb;
    bf16* wqb   = vt_ws + NELEM;        // +2MB each
    bf16* wkb   = wqb + WELEM;
    bf16* wvb   = wkb + WELEM;
    bf16* wob   = wvb + WELEM;          // ends at 40MB

    bool fast = ws_size >= (size_t)40 * 1024 * 1024;   // constant across calls

    if (fast) {
        cvt_all_kernel<<<8192, 256, 0, stream>>>(x, Wq, Wk, Wv, Wo,
                                                 xb, wqb, wkb, wvb, wob);
        gemm_qkv_fast<<<dim3(32, 24), 256, 0, stream>>>(
            xb, wqb, wkb, wvb, bq, bk, bv, q_ws, k_ws, vt_ws);
        attn_kernel<<<1024, 256, 0, stream>>>(q_ws, k_ws, vt_ws, o_ws);
        gemm_out_fast<<<dim3(32, 8), 256, 0, stream>>>(o_ws, wob, bo, out);
    } else {
        cvt_kernel<<<4096, 256, 0, stream>>>(x, xb);
        gemm_qkv_f32w<<<dim3(32, 24), 256, 0, stream>>>(
            xb, Wq, Wk, Wv, bq, bk, bv, q_ws, k_ws, vt_ws);
        attn_kernel<<<1024, 256, 0, stream>>>(q_ws, k_ws, vt_ws, o_ws);
        gemm_out_f32w<<<dim3(32, 8), 256, 0, stream>>>(o_ws, Wo, bo, out);
    }
}